// Round 3
// baseline (675.223 us; speedup 1.0000x reference)
//
#include <hip/hip_runtime.h>
#include <hip/hip_bf16.h>

// Problem constants (fixed by the reference)
#define HD   4096      // hidden
#define ID   14336     // intermediate
#define NB   64        // batch
#define NLUTN 4096
#define DKS  8         // down-proj K split across grid.y

typedef __attribute__((ext_vector_type(8))) short short8;   // 8 x bf16 bits
typedef __attribute__((ext_vector_type(4))) float f32x4;    // MFMA accumulator

__device__ __forceinline__ unsigned short f2bf(float f) {
  __hip_bfloat16 h = __float2bfloat16(f);
  return __builtin_bit_cast(unsigned short, h);
}

// async global->LDS, 16B per lane, dest = uniform base + lane*16 (linear)
__device__ __forceinline__ void gll16(const int* g, void* l) {
  __builtin_amdgcn_global_load_lds(
      (const __attribute__((address_space(1))) int*)g,
      (__attribute__((address_space(3))) int*)l, 16, 0, 0);
}

// ---------------------------------------------------------------------------
// prep: k-blocked bf16 activations. xgB unit u = (k>>3)*64+b holds 8 bf16
// of (x[b][k0..k0+8) * gsr), xuB likewise.
// ---------------------------------------------------------------------------
__global__ __launch_bounds__(256) void prep_kernel(
    const float* __restrict__ x, const float* __restrict__ gsr,
    const float* __restrict__ usr,
    unsigned short* __restrict__ xgB, unsigned short* __restrict__ xuB)
{
  int u = blockIdx.x * 256 + threadIdx.x;     // 0..32767
  int b = u & 63, k8 = u >> 6;
  const float* xp = x + (size_t)b * HD + k8 * 8;
  float4 x0 = ((const float4*)xp)[0];
  float4 x1 = ((const float4*)xp)[1];
  const float* gp = gsr + k8 * 8;
  const float* up = usr + k8 * 8;
  float4 g0 = ((const float4*)gp)[0], g1 = ((const float4*)gp)[1];
  float4 u0 = ((const float4*)up)[0], u1 = ((const float4*)up)[1];
  ushort4 og0 = make_ushort4(f2bf(x0.x*g0.x), f2bf(x0.y*g0.y), f2bf(x0.z*g0.z), f2bf(x0.w*g0.w));
  ushort4 og1 = make_ushort4(f2bf(x1.x*g1.x), f2bf(x1.y*g1.y), f2bf(x1.z*g1.z), f2bf(x1.w*g1.w));
  ushort4 ou0 = make_ushort4(f2bf(x0.x*u0.x), f2bf(x0.y*u0.y), f2bf(x0.z*u0.z), f2bf(x0.w*u0.w));
  ushort4 ou1 = make_ushort4(f2bf(x1.x*u1.x), f2bf(x1.y*u1.y), f2bf(x1.z*u1.z), f2bf(x1.w*u1.w));
  ((ushort4*)(xgB + (size_t)u*8))[0] = og0;
  ((ushort4*)(xgB + (size_t)u*8))[1] = og1;
  ((ushort4*)(xuB + (size_t)u*8))[0] = ou0;
  ((ushort4*)(xuB + (size_t)u*8))[1] = ou1;
}

// ---------------------------------------------------------------------------
// gate+up. Block = 128 thr = 2 waves. MAT-SPLIT: wave0 computes gate,
// wave1 computes up, SAME 16 I-rows, full K=4096 each (no k-split).
// Codes: ring-3 LDS staging via global_load_lds, counted vmcnt(6) wait
// (never 0) -> stage(i) has ~2 iterations of latency budget.
// x: depth-1 register prefetch, issued BEFORE the stage so the compiler's
// x-wait is vmcnt(8), not 0. Epilogue: wave1 dumps acc via 4KB red,
// wave0 applies silu(g)*u*dsr and writes k-blocked hidden.
// grid = ID/16 = 896. LDS: 16K LUT + 12K ring + 4K red = 32KB.
// ---------------------------------------------------------------------------
__global__ __launch_bounds__(128, 2) void gate_up_kernel(
    const int* __restrict__ gw, const int* __restrict__ uw,
    const float* __restrict__ lutg_f, const float* __restrict__ lutu_f,
    const unsigned short* __restrict__ xgB, const unsigned short* __restrict__ xuB,
    const float* __restrict__ gsl, const float* __restrict__ usl,
    const float* __restrict__ dsr,
    unsigned short* __restrict__ hidB)
{
  __shared__ unsigned short lutg[NLUTN];
  __shared__ unsigned short lutu[NLUTN];
  __shared__ __align__(16) int cbuf[2][3][512];   // [wave][ring][16r x 32k]
  __shared__ f32x4 red[4][64];

  const int tid  = threadIdx.x;
  const int lane = tid & 63;
  const int w    = tid >> 6;

  for (int i = tid; i < NLUTN/4; i += 128) {
    float4 g = ((const float4*)lutg_f)[i];
    float4 u = ((const float4*)lutu_f)[i];
    ((ushort4*)lutg)[i] = make_ushort4(f2bf(g.x), f2bf(g.y), f2bf(g.z), f2bf(g.w));
    ((ushort4*)lutu)[i] = make_ushort4(f2bf(u.x), f2bf(u.y), f2bf(u.z), f2bf(u.w));
  }
  __syncthreads();

  // per-wave matrix selection
  const unsigned short* lut = w ? lutu : lutg;
  const int* cw = w ? uw : gw;
  const unsigned short* xB = w ? xuB : xgB;

  const int col  = lane & 15;
  const int quad = lane >> 4;
  const int m0   = blockIdx.x * 16;
  const int r8   = lane >> 3;          // staging: row within 8-row half
  const int j    = lane & 7;           // staging: 16B unit within row
  const int jx   = (j ^ r8) << 2;      // pre-swizzled src offset (ints)
  const int xsw  = (col & 7) << 4;     // read-side XOR (bytes)

  const int* src0 = cw + (size_t)(m0 + r8) * HD + jx;
  const int* src1 = cw + (size_t)(m0 + 8 + r8) * HD + jx;

  int* b0 = &cbuf[w][0][0];
  int* b1 = &cbuf[w][1][0];
  int* b2 = &cbuf[w][2][0];

  const f32x4 z = {0.f, 0.f, 0.f, 0.f};
  f32x4 acc[4] = {z, z, z, z};

  // prologue: stage(0)->b0 ; x(0) ; stage(1)->b1   (order matters for vmcnt)
  gll16(src0 + 0, b0); gll16(src1 + 0, (char*)b0 + 1024);
  short8 xv[4];
  {
    size_t xo = ((size_t)quad * 64 + col) * 8;
    #pragma unroll
    for (int t = 0; t < 4; ++t)
      xv[t] = __builtin_bit_cast(short8, *(const int4*)(xB + xo + t*128));
  }
  gll16(src0 + 32, b1); gll16(src1 + 32, (char*)b1 + 1024);

  const int NIT = HD / 32;             // 128
  for (int it = 0; it < NIT; ++it) {
    // counted wait: allow {x(it):4, stage(it+1):2} in flight; forces only
    // stage(it) (issued 2 iterations ago) to completion. NEVER vmcnt(0).
    asm volatile("s_waitcnt vmcnt(6)" ::: "memory");
    __builtin_amdgcn_sched_barrier(0);

    // codes from swizzled ring buffer b0 + LUT gather
    const char* cg = (const char*)b0;
    int4 ca = *(const int4*)(cg + col*128 + (((quad<<5) + 0 ) ^ xsw));
    int4 cb = *(const int4*)(cg + col*128 + (((quad<<5) + 16) ^ xsw));
    short8 af;
    af[0] = (short)lut[ca.x]; af[1] = (short)lut[ca.y];
    af[2] = (short)lut[ca.z]; af[3] = (short)lut[ca.w];
    af[4] = (short)lut[cb.x]; af[5] = (short)lut[cb.y];
    af[6] = (short)lut[cb.z]; af[7] = (short)lut[cb.w];

    // depth-1 x prefetch (before the stage -> compiler x-wait stays counted)
    const int kx = (it+1 < NIT) ? (it+1)*32 : 0;
    short8 xn[4];
    {
      size_t xo = ((size_t)((kx >> 3) + quad) * 64 + col) * 8;
      #pragma unroll
      for (int t = 0; t < 4; ++t)
        xn[t] = __builtin_bit_cast(short8, *(const int4*)(xB + xo + t*128));
    }

    // stage it+2 -> b2
    const int ks = (it+2 < NIT) ? (it+2)*32 : 0;
    gll16(src0 + ks, b2); gll16(src1 + ks, (char*)b2 + 1024);

    #pragma unroll
    for (int t = 0; t < 4; ++t)
      acc[t] = __builtin_amdgcn_mfma_f32_16x16x32_bf16(af, xv[t], acc[t], 0, 0, 0);

    #pragma unroll
    for (int t = 0; t < 4; ++t) xv[t] = xn[t];
    int* tmp = b0; b0 = b1; b1 = b2; b2 = tmp;
  }

  // combine: wave1 (up) publishes, wave0 (gate) finishes
  if (w == 1) {
    #pragma unroll
    for (int t = 0; t < 4; ++t) red[t][lane] = acc[t];
  }
  __syncthreads();
  if (w == 0) {
    const int mrow = m0 + quad * 4;
    float sg[4], su[4], sd[4];
    #pragma unroll
    for (int r = 0; r < 4; ++r) {
      sg[r] = 0.02f * gsl[mrow + r];
      su[r] = 0.02f * usl[mrow + r];
      sd[r] = dsr[mrow + r];
    }
    #pragma unroll
    for (int t = 0; t < 4; ++t) {
      f32x4 au = red[t][lane];
      int b = t*16 + col;
      float g0 = acc[t][0]*sg[0], u0 = au[0]*su[0];
      float g1 = acc[t][1]*sg[1], u1 = au[1]*su[1];
      float g2 = acc[t][2]*sg[2], u2 = au[2]*su[2];
      float g3 = acc[t][3]*sg[3], u3 = au[3]*su[3];
      ushort4 hv;
      hv.x = f2bf((g0 / (1.f + __expf(-g0))) * u0 * sd[0]);
      hv.y = f2bf((g1 / (1.f + __expf(-g1))) * u1 * sd[1]);
      hv.z = f2bf((g2 / (1.f + __expf(-g2))) * u2 * sd[2]);
      hv.w = f2bf((g3 / (1.f + __expf(-g3))) * u3 * sd[3]);
      // k-blocked hidden: unit (i>>3)*64+b, sub-offset i&7
      *(ushort4*)(hidB + ((size_t)((mrow >> 3)*64 + b))*8 + (quad & 1)*4) = hv;
    }
  }
}

// ---------------------------------------------------------------------------
// down: out[b][h] = 0.02*dsl[h] * sum_i hidden[b][i]*lut_d[dw[h,i]]
// Block = 2 waves, wave w owns rows m0+w*16..+16 independently (no reduce).
// Same ring-3 counted-vmcnt pipeline. grid (HD/32, DKS) = (128, 8).
// LDS: 8K LUT + 12K ring = 20KB -> ~8 waves/CU (grid-capped at 8).
// ---------------------------------------------------------------------------
__global__ __launch_bounds__(128, 2) void down_kernel(
    const int* __restrict__ dw, const float* __restrict__ lutd_f,
    const unsigned short* __restrict__ hidB,
    const float* __restrict__ dsl,
    float* __restrict__ out)
{
  __shared__ unsigned short lutd[NLUTN];
  __shared__ __align__(16) int cbuf[2][3][512];

  const int tid  = threadIdx.x;
  const int lane = tid & 63;
  const int w    = tid >> 6;

  for (int i = tid; i < NLUTN/4; i += 128) {
    float4 d = ((const float4*)lutd_f)[i];
    ((ushort4*)lutd)[i] = make_ushort4(f2bf(d.x), f2bf(d.y), f2bf(d.z), f2bf(d.w));
  }
  __syncthreads();

  const int col  = lane & 15;
  const int quad = lane >> 4;
  const int m0   = blockIdx.x * 32 + w * 16;
  const int r8   = lane >> 3;
  const int j    = lane & 7;
  const int jx   = (j ^ r8) << 2;
  const int xsw  = (col & 7) << 4;

  const int kbeg = blockIdx.y * (ID / DKS);   // 1792-wide K slab
  const int NIT  = (ID / DKS) / 32;           // 56

  const int* src0 = dw + (size_t)(m0 + r8) * ID + kbeg + jx;
  const int* src1 = dw + (size_t)(m0 + 8 + r8) * ID + kbeg + jx;

  int* b0 = &cbuf[w][0][0];
  int* b1 = &cbuf[w][1][0];
  int* b2 = &cbuf[w][2][0];

  const f32x4 z = {0.f, 0.f, 0.f, 0.f};
  f32x4 acc[4] = {z, z, z, z};

  gll16(src0 + 0, b0); gll16(src1 + 0, (char*)b0 + 1024);
  short8 xv[4];
  {
    size_t xo = ((size_t)((kbeg >> 3) + quad) * 64 + col) * 8;
    #pragma unroll
    for (int t = 0; t < 4; ++t)
      xv[t] = __builtin_bit_cast(short8, *(const int4*)(hidB + xo + t*128));
  }
  gll16(src0 + 32, b1); gll16(src1 + 32, (char*)b1 + 1024);

  for (int it = 0; it < NIT; ++it) {
    asm volatile("s_waitcnt vmcnt(6)" ::: "memory");
    __builtin_amdgcn_sched_barrier(0);

    const char* cd = (const char*)b0;
    int4 ca = *(const int4*)(cd + col*128 + (((quad<<5) + 0 ) ^ xsw));
    int4 cb = *(const int4*)(cd + col*128 + (((quad<<5) + 16) ^ xsw));
    short8 af;
    af[0] = (short)lutd[ca.x]; af[1] = (short)lutd[ca.y];
    af[2] = (short)lutd[ca.z]; af[3] = (short)lutd[ca.w];
    af[4] = (short)lutd[cb.x]; af[5] = (short)lutd[cb.y];
    af[6] = (short)lutd[cb.z]; af[7] = (short)lutd[cb.w];

    const int kx = (it+1 < NIT) ? kbeg + (it+1)*32 : kbeg;
    short8 xn[4];
    {
      size_t xo = ((size_t)((kx >> 3) + quad) * 64 + col) * 8;
      #pragma unroll
      for (int t = 0; t < 4; ++t)
        xn[t] = __builtin_bit_cast(short8, *(const int4*)(hidB + xo + t*128));
    }

    const int ks = (it+2 < NIT) ? (it+2)*32 : 0;
    gll16(src0 + ks, b2); gll16(src1 + ks, (char*)b2 + 1024);

    #pragma unroll
    for (int t = 0; t < 4; ++t)
      acc[t] = __builtin_amdgcn_mfma_f32_16x16x32_bf16(af, xv[t], acc[t], 0, 0, 0);

    #pragma unroll
    for (int t = 0; t < 4; ++t) xv[t] = xn[t];
    int* tmp = b0; b0 = b1; b1 = b2; b2 = tmp;
  }

  const int mrow = m0 + quad * 4;
  float sc[4];
  #pragma unroll
  for (int r = 0; r < 4; ++r) sc[r] = 0.02f * dsl[mrow + r];
  #pragma unroll
  for (int t = 0; t < 4; ++t) {
    int b = t*16 + col;
    #pragma unroll
    for (int r = 0; r < 4; ++r)
      atomicAdd(&out[(size_t)b * HD + mrow + r], acc[t][r] * sc[r]);
  }
}

// ---------------------------------------------------------------------------
extern "C" void kernel_launch(void* const* d_in, const int* in_sizes, int n_in,
                              void* d_out, int out_size, void* d_ws, size_t ws_size,
                              hipStream_t stream) {
  const float* x    = (const float*)d_in[0];
  const float* lutg = (const float*)d_in[1];
  const float* lutu = (const float*)d_in[2];
  const float* lutd = (const float*)d_in[3];
  const int*   gw   = (const int*)d_in[4];
  const int*   uw   = (const int*)d_in[5];
  const int*   dw   = (const int*)d_in[6];
  const float* gsl  = (const float*)d_in[7];
  const float* gsr  = (const float*)d_in[8];
  const float* usl  = (const float*)d_in[9];
  const float* usr  = (const float*)d_in[10];
  const float* dsl  = (const float*)d_in[11];
  const float* dsr  = (const float*)d_in[12];
  float* out = (float*)d_out;

  // ws layout: xgB (512KB) | xuB (512KB) | hidB (1.75MB)
  unsigned short* xgB  = (unsigned short*)d_ws;
  unsigned short* xuB  = xgB + (size_t)NB * HD;
  unsigned short* hidB = xuB + (size_t)NB * HD;

  hipMemsetAsync(d_out, 0, (size_t)NB * HD * sizeof(float), stream);
  prep_kernel<<<(NB*HD/8 + 255)/256, 256, 0, stream>>>(x, gsr, usr, xgB, xuB);
  gate_up_kernel<<<ID/16, 128, 0, stream>>>(gw, uw, lutg, lutu, xgB, xuB,
                                            gsl, usl, dsr, hidB);
  down_kernel<<<dim3(HD/32, DKS), 128, 0, stream>>>(dw, lutd, hidB, dsl, out);
}

// Round 4
// 651.302 us; speedup vs baseline: 1.0367x; 1.0367x over previous
//
#include <hip/hip_runtime.h>
#include <hip/hip_bf16.h>

// Problem constants (fixed by the reference)
#define HD   4096      // hidden
#define ID   14336     // intermediate
#define NB   64        // batch
#define NLUTN 4096
#define DKS  8         // down-proj K split across grid.y

typedef __attribute__((ext_vector_type(8))) short short8;   // 8 x bf16 bits
typedef __attribute__((ext_vector_type(4))) float f32x4;    // MFMA accumulator

__device__ __forceinline__ unsigned short f2bf(float f) {
  __hip_bfloat16 h = __float2bfloat16(f);
  return __builtin_bit_cast(unsigned short, h);
}

// async global->LDS, 16B per lane, dest = wave-uniform base + lane*16 (linear)
__device__ __forceinline__ void gll16(const int* g, void* l) {
  __builtin_amdgcn_global_load_lds(
      (const __attribute__((address_space(1))) int*)g,
      (__attribute__((address_space(3))) int*)l, 16, 0, 0);
}

// ---------------------------------------------------------------------------
// prep: k-blocked bf16 activations. xgB unit u = (k>>3)*64+b holds 8 bf16
// of (x[b][k0..k0+8) * gsr), xuB likewise.
// ---------------------------------------------------------------------------
__global__ __launch_bounds__(256) void prep_kernel(
    const float* __restrict__ x, const float* __restrict__ gsr,
    const float* __restrict__ usr,
    unsigned short* __restrict__ xgB, unsigned short* __restrict__ xuB)
{
  int u = blockIdx.x * 256 + threadIdx.x;     // 0..32767
  int b = u & 63, k8 = u >> 6;
  const float* xp = x + (size_t)b * HD + k8 * 8;
  float4 x0 = ((const float4*)xp)[0];
  float4 x1 = ((const float4*)xp)[1];
  const float* gp = gsr + k8 * 8;
  const float* up = usr + k8 * 8;
  float4 g0 = ((const float4*)gp)[0], g1 = ((const float4*)gp)[1];
  float4 u0 = ((const float4*)up)[0], u1 = ((const float4*)up)[1];
  ushort4 og0 = make_ushort4(f2bf(x0.x*g0.x), f2bf(x0.y*g0.y), f2bf(x0.z*g0.z), f2bf(x0.w*g0.w));
  ushort4 og1 = make_ushort4(f2bf(x1.x*g1.x), f2bf(x1.y*g1.y), f2bf(x1.z*g1.z), f2bf(x1.w*g1.w));
  ushort4 ou0 = make_ushort4(f2bf(x0.x*u0.x), f2bf(x0.y*u0.y), f2bf(x0.z*u0.z), f2bf(x0.w*u0.w));
  ushort4 ou1 = make_ushort4(f2bf(x1.x*u1.x), f2bf(x1.y*u1.y), f2bf(x1.z*u1.z), f2bf(x1.w*u1.w));
  ((ushort4*)(xgB + (size_t)u*8))[0] = og0;
  ((ushort4*)(xgB + (size_t)u*8))[1] = og1;
  ((ushort4*)(xuB + (size_t)u*8))[0] = ou0;
  ((ushort4*)(xuB + (size_t)u*8))[1] = ou1;
}

// ---------------------------------------------------------------------------
// gate+up. Block = 256 thr = 4 waves, M_block = 64 I-rows, full K = 4096.
// Wave w: matrix m = w>>1 (0=gate,1=up), row-half r = w&1 (rows m0+r*32..+32).
// Per k32 iteration the BLOCK stages: 16KB codes (4 gll16/wave, own rows) +
// 8KB x (2 gll16/wave) into a ring-4 LDS arena. All fragment reads are
// ds_read_b128. One raw s_barrier per iter; counted vmcnt(12) (never 0).
// Epilogue: up waves publish acc via LDS overlay, gate waves apply
// silu(g)*u*dsr and store k-blocked hidden.
// grid = ID/64 = 224 blocks. LDS: 16K LUT + 64K code ring + 32K x ring = 112KB.
// ---------------------------------------------------------------------------
__global__ __launch_bounds__(256, 1) void gate_up_kernel(
    const int* __restrict__ gw, const int* __restrict__ uw,
    const float* __restrict__ lutg_f, const float* __restrict__ lutu_f,
    const unsigned short* __restrict__ xgB, const unsigned short* __restrict__ xuB,
    const float* __restrict__ gsl, const float* __restrict__ usl,
    const float* __restrict__ dsr,
    unsigned short* __restrict__ hidB)
{
  __shared__ unsigned short lutg[NLUTN];                    // 8KB
  __shared__ unsigned short lutu[NLUTN];                    // 8KB
  __shared__ __align__(16) char arena[4*4*4096 + 4*2*4096]; // 64K codes + 32K x

  const int tid  = threadIdx.x;
  const int lane = tid & 63;
  const int w    = tid >> 6;           // wave 0..3
  const int m    = w >> 1;             // matrix: 0 gate, 1 up
  const int r    = w & 1;              // row half

  for (int i = tid; i < NLUTN/4; i += 256) {
    float4 g = ((const float4*)lutg_f)[i];
    float4 u = ((const float4*)lutu_f)[i];
    ((ushort4*)lutg)[i] = make_ushort4(f2bf(g.x), f2bf(g.y), f2bf(g.z), f2bf(g.w));
    ((ushort4*)lutu)[i] = make_ushort4(f2bf(u.x), f2bf(u.y), f2bf(u.z), f2bf(u.w));
  }
  __syncthreads();   // full drain: vmcnt clean slate before the counted pipeline

  const unsigned short* lut = m ? lutu : lutg;
  const int* cw = m ? uw : gw;
  const unsigned short* xB = m ? xuB : xgB;

  const int col  = lane & 15;
  const int quad = lane >> 4;
  const int m0   = blockIdx.x * 64;
  const int r8   = lane >> 3;          // staging: row within 8-row group
  const int j    = lane & 7;           // staging: 16B unit within row
  const int jx   = (j ^ r8) << 2;      // pre-swizzled src offset (ints)
  const int xsw  = (col & 7) << 4;     // read-side XOR (bytes)

  // code sources: 4 groups of 8 rows for this wave (rows m0 + r*32 + g*8 + r8)
  const int* csrc[4];
  #pragma unroll
  for (int g = 0; g < 4; ++g)
    csrc[g] = cw + (size_t)(m0 + r*32 + g*8 + r8) * HD + jx;
  // x staging source (this wave stages parts r*2, r*2+1 of matrix m's chunk)
  const int* xsrc = (const int*)xB + lane * 4;

  const f32x4 z = {0.f, 0.f, 0.f, 0.f};
  f32x4 acc[2][4] = {{z,z,z,z},{z,z,z,z}};

  const int NIT = HD / 32;             // 128

  #define GU_STAGE(IT, RR) {                                          \
    int ko_ = ((IT) < NIT) ? (IT)*32 : 0;                             \
    int xc_ = ((IT) < NIT) ? (IT)     : 0;                            \
    char* cb_ = arena + ((RR)*4 + w) * 4096;                          \
    gll16(csrc[0] + ko_, cb_);                                        \
    gll16(csrc[1] + ko_, cb_ + 1024);                                 \
    gll16(csrc[2] + ko_, cb_ + 2048);                                 \
    gll16(csrc[3] + ko_, cb_ + 3072);                                 \
    char* xb_ = arena + 65536 + ((RR)*2 + m) * 4096 + r*2048;         \
    gll16(xsrc + xc_*1024 + (r*2  )*256, xb_);                        \
    gll16(xsrc + xc_*1024 + (r*2+1)*256, xb_ + 1024);                 \
  }

  GU_STAGE(0, 0);
  GU_STAGE(1, 1);

  for (int it = 0; it < NIT; ++it) {
    GU_STAGE(it + 2, (it + 2) & 3);
    // outstanding: stage(it),(it+1),(it+2) = 18; wait to 12 => stage(it) done
    asm volatile("s_waitcnt vmcnt(12)" ::: "memory");
    __builtin_amdgcn_s_barrier();      // everyone's stage(it) landed
    __builtin_amdgcn_sched_barrier(0);

    const char* cb = arena + ((it & 3)*4 + w) * 4096;
    const char* xb = arena + 65536 + ((it & 3)*2 + m) * 4096;

    short8 af[2];
    #pragma unroll
    for (int s = 0; s < 2; ++s) {
      int4 ca = *(const int4*)(cb + s*2048 + col*128 + (((quad<<5)     ) ^ xsw));
      int4 cc = *(const int4*)(cb + s*2048 + col*128 + (((quad<<5) + 16) ^ xsw));
      af[s][0] = (short)lut[ca.x]; af[s][1] = (short)lut[ca.y];
      af[s][2] = (short)lut[ca.z]; af[s][3] = (short)lut[ca.w];
      af[s][4] = (short)lut[cc.x]; af[s][5] = (short)lut[cc.y];
      af[s][6] = (short)lut[cc.z]; af[s][7] = (short)lut[cc.w];
    }
    short8 xv[4];
    #pragma unroll
    for (int t = 0; t < 4; ++t)
      xv[t] = __builtin_bit_cast(short8,
                *(const int4*)(xb + quad*1024 + t*256 + col*16));

    #pragma unroll
    for (int t = 0; t < 4; ++t)
      #pragma unroll
      for (int s = 0; s < 2; ++s)
        acc[s][t] = __builtin_amdgcn_mfma_f32_16x16x32_bf16(af[s], xv[t], acc[s][t], 0, 0, 0);
    // ring-4: stage(it+3) (next top) targets slot (it-1)&3, which all waves
    // finished reading before this iteration's barrier -> no second barrier.
  }
  #undef GU_STAGE

  // drain pending dummy DMAs before overlaying the arena with 'red'
  asm volatile("s_waitcnt vmcnt(0)" ::: "memory");
  __syncthreads();

  if (w >= 2) {   // up waves publish
    #pragma unroll
    for (int s = 0; s < 2; ++s)
      #pragma unroll
      for (int t = 0; t < 4; ++t)
        *(f32x4*)(arena + ((((w-2)*2 + s)*4 + t)*64 + lane)*16) = acc[s][t];
  }
  __syncthreads();
  if (w < 2) {    // gate waves combine + epilogue
    #pragma unroll
    for (int s = 0; s < 2; ++s) {
      const int mrow = m0 + w*32 + s*16 + quad*4;
      float sg[4], su[4], sd[4];
      #pragma unroll
      for (int rr = 0; rr < 4; ++rr) {
        sg[rr] = 0.02f * gsl[mrow + rr];
        su[rr] = 0.02f * usl[mrow + rr];
        sd[rr] = dsr[mrow + rr];
      }
      #pragma unroll
      for (int t = 0; t < 4; ++t) {
        f32x4 au = *(const f32x4*)(arena + (((w*2 + s)*4 + t)*64 + lane)*16);
        int b = t*16 + col;
        float g0 = acc[s][t][0]*sg[0], u0 = au[0]*su[0];
        float g1 = acc[s][t][1]*sg[1], u1 = au[1]*su[1];
        float g2 = acc[s][t][2]*sg[2], u2 = au[2]*su[2];
        float g3 = acc[s][t][3]*sg[3], u3 = au[3]*su[3];
        ushort4 hv;
        hv.x = f2bf((g0 / (1.f + __expf(-g0))) * u0 * sd[0]);
        hv.y = f2bf((g1 / (1.f + __expf(-g1))) * u1 * sd[1]);
        hv.z = f2bf((g2 / (1.f + __expf(-g2))) * u2 * sd[2]);
        hv.w = f2bf((g3 / (1.f + __expf(-g3))) * u3 * sd[3]);
        *(ushort4*)(hidB + ((size_t)((mrow >> 3)*64 + b))*8 + (quad & 1)*4) = hv;
      }
    }
  }
}

// ---------------------------------------------------------------------------
// down: out[b][h] = 0.02*dsl[h] * sum_i hidden[b][i]*lut_d[dw[h,i]]
// Block = 4 waves, M_block = 64 h-rows (wave w: rows m0+w*16..+16), K-slab
// = ID/DKS per blockIdx.y. Ring-4 staging: codes 8KB + shared hid x 4KB per
// iter. TRANSPOSED mfma(x, codes) so D col = h -> epilogue atomics land in
// 4x64B contiguous segments per instruction (16x less epilogue traffic).
// grid (HD/64, DKS) = (64, 8). LDS: 8K LUT + 32K codes + 16K x = 56KB.
// ---------------------------------------------------------------------------
__global__ __launch_bounds__(256, 2) void down_kernel(
    const int* __restrict__ dw, const float* __restrict__ lutd_f,
    const unsigned short* __restrict__ hidB,
    const float* __restrict__ dsl,
    float* __restrict__ out)
{
  __shared__ unsigned short lutd[NLUTN];                    // 8KB
  __shared__ __align__(16) char arena[4*4*2048 + 4*4096];   // 32K codes + 16K x

  const int tid  = threadIdx.x;
  const int lane = tid & 63;
  const int w    = tid >> 6;

  for (int i = tid; i < NLUTN/4; i += 256) {
    float4 d = ((const float4*)lutd_f)[i];
    ((ushort4*)lutd)[i] = make_ushort4(f2bf(d.x), f2bf(d.y), f2bf(d.z), f2bf(d.w));
  }
  __syncthreads();

  const int col  = lane & 15;
  const int quad = lane >> 4;
  const int m0   = blockIdx.x * 64;            // h-rows of the block
  const int r8   = lane >> 3;
  const int j    = lane & 7;
  const int jx   = (j ^ r8) << 2;
  const int xsw  = (col & 7) << 4;

  const int kbeg = blockIdx.y * (ID / DKS);    // 1792-wide K slab
  const int NIT  = (ID / DKS) / 32;            // 56

  const int* csrc0 = dw + (size_t)(m0 + w*16     + r8) * ID + kbeg + jx;
  const int* csrc1 = dw + (size_t)(m0 + w*16 + 8 + r8) * ID + kbeg + jx;
  const int* xsrc  = (const int*)hidB + kbeg*32 + lane*4;

  const f32x4 z = {0.f, 0.f, 0.f, 0.f};
  f32x4 acc[4] = {z, z, z, z};

  #define DN_STAGE(IT, RR) {                                          \
    int ko_ = ((IT) < NIT) ? (IT)*32 : 0;                             \
    int xc_ = ((IT) < NIT) ? (IT)     : 0;                            \
    char* cb_ = arena + ((RR)*4 + w) * 2048;                          \
    gll16(csrc0 + ko_, cb_);                                          \
    gll16(csrc1 + ko_, cb_ + 1024);                                   \
    gll16(xsrc + xc_*1024 + w*256, arena + 32768 + (RR)*4096 + w*1024); \
  }

  DN_STAGE(0, 0);
  DN_STAGE(1, 1);

  for (int it = 0; it < NIT; ++it) {
    DN_STAGE(it + 2, (it + 2) & 3);
    asm volatile("s_waitcnt vmcnt(6)" ::: "memory");   // stage(it) done
    __builtin_amdgcn_s_barrier();
    __builtin_amdgcn_sched_barrier(0);

    const char* cb = arena + ((it & 3)*4 + w) * 2048;
    const char* xb = arena + 32768 + (it & 3) * 4096;

    int4 ca = *(const int4*)(cb + col*128 + (((quad<<5)     ) ^ xsw));
    int4 cc = *(const int4*)(cb + col*128 + (((quad<<5) + 16) ^ xsw));
    short8 af;
    af[0] = (short)lutd[ca.x]; af[1] = (short)lutd[ca.y];
    af[2] = (short)lutd[ca.z]; af[3] = (short)lutd[ca.w];
    af[4] = (short)lutd[cc.x]; af[5] = (short)lutd[cc.y];
    af[6] = (short)lutd[cc.z]; af[7] = (short)lutd[cc.w];

    short8 xv[4];
    #pragma unroll
    for (int t = 0; t < 4; ++t)
      xv[t] = __builtin_bit_cast(short8,
                *(const int4*)(xb + quad*1024 + t*256 + col*16));

    // TRANSPOSED: A = x (rows = batch), B = codes (cols = h)
    #pragma unroll
    for (int t = 0; t < 4; ++t)
      acc[t] = __builtin_amdgcn_mfma_f32_16x16x32_bf16(xv[t], af, acc[t], 0, 0, 0);
  }
  #undef DN_STAGE

  // Epilogue: D[row][col] -> b = t*16 + quad*4 + reg, h = m0 + w*16 + col.
  const int h = m0 + w*16 + col;
  const float sd = 0.02f * dsl[h];
  #pragma unroll
  for (int t = 0; t < 4; ++t) {
    #pragma unroll
    for (int rr = 0; rr < 4; ++rr) {
      int b = t*16 + quad*4 + rr;
      atomicAdd(&out[(size_t)b * HD + h], acc[t][rr] * sd);
    }
  }
}

// ---------------------------------------------------------------------------
extern "C" void kernel_launch(void* const* d_in, const int* in_sizes, int n_in,
                              void* d_out, int out_size, void* d_ws, size_t ws_size,
                              hipStream_t stream) {
  const float* x    = (const float*)d_in[0];
  const float* lutg = (const float*)d_in[1];
  const float* lutu = (const float*)d_in[2];
  const float* lutd = (const float*)d_in[3];
  const int*   gw   = (const int*)d_in[4];
  const int*   uw   = (const int*)d_in[5];
  const int*   dw   = (const int*)d_in[6];
  const float* gsl  = (const float*)d_in[7];
  const float* gsr  = (const float*)d_in[8];
  const float* usl  = (const float*)d_in[9];
  const float* usr  = (const float*)d_in[10];
  const float* dsl  = (const float*)d_in[11];
  const float* dsr  = (const float*)d_in[12];
  float* out = (float*)d_out;

  // ws layout: xgB (512KB) | xuB (512KB) | hidB (1.75MB)
  unsigned short* xgB  = (unsigned short*)d_ws;
  unsigned short* xuB  = xgB + (size_t)NB * HD;
  unsigned short* hidB = xuB + (size_t)NB * HD;

  hipMemsetAsync(d_out, 0, (size_t)NB * HD * sizeof(float), stream);
  prep_kernel<<<(NB*HD/8 + 255)/256, 256, 0, stream>>>(x, gsr, usr, xgB, xuB);
  gate_up_kernel<<<ID/64, 256, 0, stream>>>(gw, uw, lutg, lutu, xgB, xuB,
                                            gsl, usl, dsr, hidB);
  down_kernel<<<dim3(HD/64, DKS), 256, 0, stream>>>(dw, lutd, hidB, dsl, out);
}